// Round 4
// baseline (436.288 us; speedup 1.0000x reference)
//
#include <hip/hip_runtime.h>
#include <hip/hip_bf16.h>

typedef unsigned short ushort_t;
typedef __attribute__((ext_vector_type(8))) short short8;
typedef __attribute__((ext_vector_type(4))) float f32x4;

#define DI __device__ __forceinline__

DI float b2f(unsigned int u16) {
  union { unsigned int i; float f; } v;
  v.i = u16 << 16;
  return v.f;
}
DI ushort_t f2b(float f) {
  union { float f; unsigned int u; } v; v.f = f;
  unsigned int r = v.u + 0x7FFFu + ((v.u >> 16) & 1u);
  return (ushort_t)(r >> 16);
}

// async global->LDS 16B copy: LDS dest is wave-uniform base + lane*16
DI void gl_lds16(const ushort_t* g, ushort_t* l) {
  __builtin_amdgcn_global_load_lds(
      (const __attribute__((address_space(1))) unsigned int*)g,
      (__attribute__((address_space(3))) unsigned int*)l, 16, 0, 0);
}

// ---------------------------------------------------------------------------
// Weight fp32 -> bf16 conversion (4 matrices in one grid-stride kernel)
// ---------------------------------------------------------------------------
__global__ void wcvt_kernel(const float* __restrict__ w0, const float* __restrict__ w1,
                            const float* __restrict__ w2, const float* __restrict__ w3,
                            ushort_t* __restrict__ o0, ushort_t* __restrict__ o1,
                            ushort_t* __restrict__ o2, ushort_t* __restrict__ o3) {
  const int n1 = 2304 * 768, n3 = 768 * 768;
  const int total = 2 * n1 + 2 * n3;
  for (int i = blockIdx.x * blockDim.x + threadIdx.x; i < total; i += gridDim.x * blockDim.x) {
    if (i < n1) o0[i] = f2b(w0[i]);
    else if (i < 2 * n1) o1[i - n1] = f2b(w1[i - n1]);
    else if (i < 2 * n1 + n3) o2[i - 2 * n1] = f2b(w2[i - 2 * n1]);
    else o3[i - 2 * n1 - n3] = f2b(w3[i - 2 * n1 - n3]);
  }
}

// ---------------------------------------------------------------------------
// GroupNorm stats, two-phase.
// ---------------------------------------------------------------------------
__global__ void gn_partial_kernel(const float* __restrict__ video,
                                  const float* __restrict__ audio,
                                  float* __restrict__ part) {
  const int bid = blockIdx.x;
  const int tid = threadIdx.x;
  float s = 0.f, ss = 0.f;
  if (bid < 2048) {
    int bg = bid >> 4, f = bid & 15;
    int b = bg >> 5, g = bg & 31;
    const float* base = video + ((size_t)((b * 16 + f) * 768 + g * 24)) * 256 + tid;
#pragma unroll
    for (int cl = 0; cl < 24; ++cl) {
      float v = base[cl * 256];
      s += v; ss += v * v;
    }
  } else {
    int a = bid - 2048;
    int bg = a >> 2, p = a & 3;
    int b = bg >> 5, g = bg & 31;
    const float* base = audio + ((size_t)(b * 768 + g * 24)) * 1024 + p * 256 + tid;
#pragma unroll
    for (int cl = 0; cl < 24; ++cl) {
      float v = base[cl * 1024];
      s += v; ss += v * v;
    }
  }
  for (int off = 32; off > 0; off >>= 1) { s += __shfl_down(s, off, 64); ss += __shfl_down(ss, off, 64); }
  __shared__ float red[8];
  int wv = tid >> 6, ln = tid & 63;
  if (ln == 0) { red[wv * 2] = s; red[wv * 2 + 1] = ss; }
  __syncthreads();
  if (tid == 0) {
    part[bid * 2] = red[0] + red[2] + red[4] + red[6];
    part[bid * 2 + 1] = red[1] + red[3] + red[5] + red[7];
  }
}

__global__ void gn_final_kernel(const float* __restrict__ part,
                                float* __restrict__ mu, float* __restrict__ rs) {
  const int tid = threadIdx.x;  // 0..255
  float s = 0.f, ss = 0.f;
  if (tid < 128) {
#pragma unroll
    for (int i = 0; i < 16; ++i) { s += part[(tid * 16 + i) * 2]; ss += part[(tid * 16 + i) * 2 + 1]; }
    const float N = 24.f * 4096.f;
    float m = s / N;
    mu[tid] = m;
    rs[tid] = rsqrtf(ss / N - m * m + 1e-5f);
  } else {
    int a = tid - 128;
#pragma unroll
    for (int i = 0; i < 4; ++i) { s += part[(2048 + a * 4 + i) * 2]; ss += part[(2048 + a * 4 + i) * 2 + 1]; }
    const float N = 24.f * 1024.f;
    float m = s / N;
    mu[tid] = m;
    rs[tid] = rsqrtf(ss / N - m * m + 1e-5f);
  }
}

// ---------------------------------------------------------------------------
// Normalize video -> token-major bf16  Xv[n][c], n = b*4096 + f*256 + hw
// ---------------------------------------------------------------------------
__global__ void norm_video_kernel(const float* __restrict__ video,
                                  const float* __restrict__ mu, const float* __restrict__ rs,
                                  const float* __restrict__ sc, const float* __restrict__ bi,
                                  ushort_t* __restrict__ Xv) {
  __shared__ float T[32][257];
  const int bx = blockIdx.x;
  const int bf = bx / 24, ct = bx % 24;
  const int b = bf >> 4, f = bf & 15;
  const int c0 = ct * 32;
  const int tid = threadIdx.x;
  for (int i = 0; i < 32; ++i) {
    int c = c0 + i;
    int g = c / 24;
    float m = mu[b * 32 + g], r = rs[b * 32 + g];
    float v = video[((size_t)((b * 16 + f) * 768 + c)) * 256 + tid];
    T[i][tid] = (v - m) * r * sc[c] + bi[c];
  }
  __syncthreads();
  for (int i = 0; i < 32; ++i) {
    int id = i * 256 + tid;
    int c = id & 31, hw = id >> 5;
    Xv[((size_t)(b * 4096 + f * 256 + hw)) * 768 + c0 + c] = f2b(T[c][hw]);
  }
}

// Normalize audio -> token-major bf16  Xa[n][c], n = b*1024 + t
__global__ void norm_audio_kernel(const float* __restrict__ audio,
                                  const float* __restrict__ mu, const float* __restrict__ rs,
                                  const float* __restrict__ sc, const float* __restrict__ bi,
                                  ushort_t* __restrict__ Xa) {
  __shared__ float T[32][257];
  const int bx = blockIdx.x;
  const int bt = bx / 24, ct = bx % 24;
  const int b = bt >> 2, t0 = (bt & 3) * 256;
  const int c0 = ct * 32;
  const int tid = threadIdx.x;
  for (int i = 0; i < 32; ++i) {
    int c = c0 + i;
    int g = c / 24;
    float m = mu[128 + b * 32 + g], r = rs[128 + b * 32 + g];
    float v = audio[((size_t)(b * 768 + c)) * 1024 + t0 + tid];
    T[i][tid] = (v - m) * r * sc[c] + bi[c];
  }
  __syncthreads();
  for (int i = 0; i < 32; ++i) {
    int id = i * 256 + tid;
    int c = id & 31, tt = id >> 5;
    Xa[((size_t)(b * 1024 + t0 + tt)) * 768 + c0 + c] = f2b(T[c][tt]);
  }
}

// ---------------------------------------------------------------------------
// 256x256 8-phase MFMA GEMM (m201-style, plain HIP):
//   BM=BN=256, BK=64, 8 waves (2M x 4N), 512 threads, 128 KiB LDS dbuf.
//   Per K-tile: 4 phases {ds_read subtile -> 16 MFMA} between raw s_barriers;
//   next tile's 8 global_load_lds all issue at phase 0; single vmcnt(0) at
//   phase 3 (3 MFMA phases of latency cover). setprio(1) around MFMA (T5).
//   XOR chunk swizzle on BOTH gl_lds source and ds_read (involution).
//   MODE 0: QKV epilogue (Q pre-scaled 0.125); MODE 1: video proj + residual.
// ---------------------------------------------------------------------------
template <int MODE>
__global__ __launch_bounds__(512, 2) void gemm256_kernel(
    const ushort_t* __restrict__ A, const ushort_t* __restrict__ W,
    const float* __restrict__ bias,
    void* __restrict__ p0, void* __restrict__ p1, void* __restrict__ p2,
    int M) {
  __shared__ ushort_t sm[65536];  // 128 KiB: [A b0|A b1|B b0|B b1] x 32KB
  const int tid = threadIdx.x;
  const int lane = tid & 63, wave = tid >> 6;
  const int quad = lane >> 4, l16 = lane & 15;
  const int nwg = gridDim.x * gridDim.y;
  const int orig = blockIdx.x + gridDim.x * blockIdx.y;
  const int lid = (orig & 7) * (nwg >> 3) + (orig >> 3);
  const int n0 = (lid % gridDim.x) * 256, m0 = (lid / gridDim.x) * 256;
  const int wm = (wave & 1) * 128, wn = (wave >> 1) * 64;

  // staging: per issue i, thread covers row i*64 + wave*8 + (lane>>3),
  // chunk slot lane&7 holds global chunk (lane&7)^(row&7)  [row&7 == lane>>3]
  const int r8 = lane >> 3, c8 = lane & 7;
  const int s8 = (c8 ^ r8) * 8;
  const ushort_t* gA = A + (size_t)(m0 + wave * 8 + r8) * 768 + s8;
  const ushort_t* gB = W + (size_t)(n0 + wave * 8 + r8) * 768 + s8;

  f32x4 acc[8][4];
#pragma unroll
  for (int i = 0; i < 8; ++i)
#pragma unroll
    for (int j = 0; j < 4; ++j) acc[i][j] = (f32x4){0.f, 0.f, 0.f, 0.f};

  auto stage = [&](int kc, int c) {
    ushort_t* lA = sm + c * 16384 + wave * 512;
    ushort_t* lB = sm + 32768 + c * 16384 + wave * 512;
#pragma unroll
    for (int i = 0; i < 4; ++i) {
      gl_lds16(gA + (size_t)i * 64 * 768 + kc, lA + i * 4096);
      gl_lds16(gB + (size_t)i * 64 * 768 + kc, lB + i * 4096);
    }
  };

  stage(0, 0);
  asm volatile("s_waitcnt vmcnt(0)" ::: "memory");
  asm volatile("s_barrier" ::: "memory");
  int cur = 0;
  for (int t = 0; t < 12; ++t) {
    const ushort_t* cA = sm + cur * 16384;
    const ushort_t* cB = sm + 32768 + cur * 16384;
    short8 bv[2][4];
#pragma unroll
    for (int ph = 0; ph < 4; ++ph) {
      const int ks = ph >> 1, imh = ph & 1;
      if (ph == 0 && t < 11) stage((t + 1) * 64, cur ^ 1);  // 8 loads, 3 phases of cover
      short8 av[4];
#pragma unroll
      for (int im = 0; im < 4; ++im) {
        int rr = wm + imh * 64 + im * 16 + l16;
        av[im] = *reinterpret_cast<const short8*>(
            cA + rr * 64 + (((ks * 4 + quad) ^ (l16 & 7)) * 8));
      }
      if ((ph & 1) == 0) {
#pragma unroll
        for (int in = 0; in < 4; ++in) {
          int rr = wn + in * 16 + l16;
          bv[ks][in] = *reinterpret_cast<const short8*>(
              cB + rr * 64 + (((ks * 4 + quad) ^ (l16 & 7)) * 8));
        }
      }
      __builtin_amdgcn_s_setprio(1);
#pragma unroll
      for (int im = 0; im < 4; ++im)
#pragma unroll
        for (int in = 0; in < 4; ++in)
          acc[imh * 4 + im][in] = __builtin_amdgcn_mfma_f32_16x16x32_bf16(
              av[im], bv[ks][in], acc[imh * 4 + im][in], 0, 0, 0);
      __builtin_amdgcn_s_setprio(0);
      if (ph == 3) asm volatile("s_waitcnt vmcnt(0)" ::: "memory");  // own t+1 stages landed
      asm volatile("s_barrier" ::: "memory");
    }
    cur ^= 1;
  }

  ushort_t* sC = sm;  // epilogue scratch [256][136] bf16 (69.6 KB, reuse)
  if (MODE == 0) {
    const int section = n0 / 768;  // 0=Q 1=K 2=V
    const int obase = n0 - section * 768;
    if (section < 2) {
      const float qs = (section == 0) ? 0.125f : 1.0f;  // fold qk scale into Q
      ushort_t* dst = (ushort_t*)(section == 0 ? p0 : p1);
#pragma unroll
      for (int ch = 0; ch < 2; ++ch) {  // column halves
        if ((wn >> 7) == ch) {
#pragma unroll
          for (int in = 0; in < 4; ++in) {
            int ol = wn + in * 16 + l16;
            float bv_ = bias[n0 + ol];
            int olh = ol & 127;
#pragma unroll
            for (int im2 = 0; im2 < 8; ++im2)
#pragma unroll
              for (int r = 0; r < 4; ++r) {
                int row = wm + (im2 >> 2) * 64 + (im2 & 3) * 16 + quad * 4 + r;
                sC[row * 136 + olh] = f2b((acc[im2][in][r] + bv_) * qs);
              }
          }
        }
        __syncthreads();
#pragma unroll
        for (int i = 0; i < 8; ++i) {
          int cid = i * 512 + tid;
          int row = cid >> 4, ck = cid & 15;
          *reinterpret_cast<uint4*>(dst + (size_t)(m0 + row) * 768 + obase + ch * 128 + ck * 8) =
              *reinterpret_cast<const uint4*>(sC + row * 136 + ck * 8);
        }
        __syncthreads();
      }
    } else {
      // V transpose: dst[o*M + m], split over m-halves
      ushort_t* dst = (ushort_t*)p2;
#pragma unroll
      for (int mh = 0; mh < 2; ++mh) {
        if ((wm >> 7) == mh) {
#pragma unroll
          for (int in = 0; in < 4; ++in) {
            int ol = wn + in * 16 + l16;
            float bv_ = bias[n0 + ol];
#pragma unroll
            for (int im2 = 0; im2 < 8; ++im2)
#pragma unroll
              for (int r = 0; r < 4; ++r) {
                int row = (im2 >> 2) * 64 + (im2 & 3) * 16 + quad * 4 + r;  // 0..127
                sC[ol * 136 + row] = f2b(acc[im2][in][r] + bv_);
              }
          }
        }
        __syncthreads();
#pragma unroll
        for (int i = 0; i < 8; ++i) {
          int cid = i * 512 + tid;
          int o = cid >> 4, ck = cid & 15;
          *reinterpret_cast<uint4*>(dst + (size_t)(obase + o) * M + m0 + mh * 128 + ck * 8) =
              *reinterpret_cast<const uint4*>(sC + o * 136 + ck * 8);
        }
        __syncthreads();
      }
    }
  } else {
    // MODE 1: video proj + residual add into fp32 [b][f][c][hw]
    float* outp = (float*)p0;
    const float* resp = (const float*)p1;
    const int b = m0 >> 12, f = (m0 >> 8) & 15;
#pragma unroll
    for (int mh = 0; mh < 2; ++mh) {
      if ((wm >> 7) == mh) {
#pragma unroll
        for (int in = 0; in < 4; ++in) {
          int ol = wn + in * 16 + l16;
          float bv_ = bias[n0 + ol];
#pragma unroll
          for (int im2 = 0; im2 < 8; ++im2)
#pragma unroll
            for (int r = 0; r < 4; ++r) {
              int row = (im2 >> 2) * 64 + (im2 & 3) * 16 + quad * 4 + r;  // hw within half
              sC[ol * 136 + row] = f2b(acc[im2][in][r] + bv_);
            }
        }
      }
      __syncthreads();
#pragma unroll
      for (int i = 0; i < 16; ++i) {
        int cid = i * 512 + tid;
        int o = cid >> 5, c4 = cid & 31;
        uint2 pk = *reinterpret_cast<const uint2*>(sC + o * 136 + c4 * 4);
        size_t gidx = ((size_t)((b * 16 + f) * 768 + n0 + o)) * 256 + mh * 128 + c4 * 4;
        float4 rv = *reinterpret_cast<const float4*>(resp + gidx);
        float4 ov;
        ov.x = rv.x + b2f(pk.x & 0xffff);
        ov.y = rv.y + b2f(pk.x >> 16);
        ov.z = rv.z + b2f(pk.y & 0xffff);
        ov.w = rv.w + b2f(pk.y >> 16);
        *reinterpret_cast<float4*>(outp + gidx) = ov;
      }
      __syncthreads();
    }
  }
}

// ---------------------------------------------------------------------------
// 128x128 2-phase GEMM (kept for the small audio proj; proven structure)
// MODE 2: audio proj (residual add)
// ---------------------------------------------------------------------------
template <int MODE>
__global__ __launch_bounds__(256) void gemm_kernel(
    const ushort_t* __restrict__ A, const ushort_t* __restrict__ W,
    const float* __restrict__ bias,
    void* __restrict__ p0, void* __restrict__ p1, void* __restrict__ p2,
    int M) {
  __shared__ ushort_t sm[32768];  // 64 KiB: dbuf x (A 16KB + B 16KB)
  const int tid = threadIdx.x;
  const int lane = tid & 63, wave = tid >> 6;
  const int quad = lane >> 4, l16 = lane & 15;
  const int nwg = gridDim.x * gridDim.y;
  const int orig = blockIdx.x + gridDim.x * blockIdx.y;
  const int lid = (orig & 7) * (nwg >> 3) + (orig >> 3);
  const int n0 = (lid % gridDim.x) * 128, m0 = (lid / gridDim.x) * 128;
  const int wm = (wave & 1) * 64, wn = (wave >> 1) * 64;

  const int srow = wave * 32 + (lane >> 3);
  const int sq = ((lane & 7) ^ (lane >> 3)) * 8;
  const ushort_t* gA = A + (size_t)(m0 + srow) * 768 + sq;
  const ushort_t* gB = W + (size_t)(n0 + srow) * 768 + sq;

  f32x4 acc[4][4];
#pragma unroll
  for (int i = 0; i < 4; ++i)
#pragma unroll
    for (int j = 0; j < 4; ++j) acc[i][j] = (f32x4){0.f, 0.f, 0.f, 0.f};

  auto stage = [&](int kc, int cur) {
    ushort_t* lA = sm + cur * 8192 + wave * 2048;
    ushort_t* lB = sm + 16384 + cur * 8192 + wave * 2048;
#pragma unroll
    for (int i = 0; i < 4; ++i) {
      gl_lds16(gA + (size_t)i * 8 * 768 + kc, lA + i * 512);
      gl_lds16(gB + (size_t)i * 8 * 768 + kc, lB + i * 512);
    }
  };

  stage(0, 0);
  __syncthreads();
  int cur = 0;
  for (int t = 0; t < 12; ++t) {
    if (t < 11) stage((t + 1) * 64, cur ^ 1);
    const ushort_t* cA = sm + cur * 8192;
    const ushort_t* cB = sm + 16384 + cur * 8192;
#pragma unroll
    for (int ks = 0; ks < 2; ++ks) {
      short8 av[4], bv[4];
#pragma unroll
      for (int im = 0; im < 4; ++im) {
        int rr = wm + im * 16 + l16;
        av[im] = *reinterpret_cast<const short8*>(
            cA + rr * 64 + (((ks * 4 + quad) ^ (rr & 7)) * 8));
      }
#pragma unroll
      for (int in = 0; in < 4; ++in) {
        int rr = wn + in * 16 + l16;
        bv[in] = *reinterpret_cast<const short8*>(
            cB + rr * 64 + (((ks * 4 + quad) ^ (rr & 7)) * 8));
      }
#pragma unroll
      for (int im = 0; im < 4; ++im)
#pragma unroll
        for (int in = 0; in < 4; ++in)
          acc[im][in] = __builtin_amdgcn_mfma_f32_16x16x32_bf16(av[im], bv[in], acc[im][in], 0, 0, 0);
    }
    __syncthreads();
    cur ^= 1;
  }

  ushort_t* sC = sm;  // epilogue scratch [128][136] bf16
#pragma unroll
  for (int in = 0; in < 4; ++in) {
    int ol = wn + in * 16 + l16;
    float bv_ = bias[n0 + ol];
#pragma unroll
    for (int im = 0; im < 4; ++im)
#pragma unroll
      for (int r = 0; r < 4; ++r) {
        int mr = wm + im * 16 + quad * 4 + r;
        sC[ol * 136 + mr] = f2b(acc[im][in][r] + bv_);
      }
  }
  __syncthreads();
  float* outp = (float*)p0;
  const float* resp = (const float*)p1;
#pragma unroll
  for (int i = 0; i < 16; ++i) {
    int cid = i * 256 + tid;
    int o = cid >> 5, ch = cid & 31;
    uint2 pk = *reinterpret_cast<const uint2*>(sC + o * 136 + ch * 4);
    int b = m0 >> 10, t0 = m0 & 1023;
    size_t gidx = ((size_t)(b * 768 + n0 + o)) * 1024 + t0 + ch * 4;
    float4 rv = *reinterpret_cast<const float4*>(resp + gidx);
    float4 ov;
    ov.x = rv.x + b2f(pk.x & 0xffff);
    ov.y = rv.y + b2f(pk.x >> 16);
    ov.z = rv.z + b2f(pk.y & 0xffff);
    ov.w = rv.w + b2f(pk.y >> 16);
    *reinterpret_cast<float4*>(outp + gidx) = ov;
  }
  (void)p2; (void)M;
}

// ---------------------------------------------------------------------------
// MFMA flash attention over contiguous windows (shift=0).
// Async gl_lds16 staging (XOR-swizzled both sides), separate Q/K/V buffers,
// V double-buffered; V(t+1) issued before QK(t), K(t+1) after mid barrier.
// Q is pre-scaled by 0.125 in the QKV GEMM epilogue.
// ---------------------------------------------------------------------------
template <int QW, int SW>
__global__ __launch_bounds__(256) void attn_mfma_kernel(
    const ushort_t* __restrict__ Qt, const ushort_t* __restrict__ Kt,
    const ushort_t* __restrict__ Vc, ushort_t* __restrict__ Ot,
    int TQb, int TSb, int Ms) {
  __shared__ ushort_t sm[37376];       // 74752 B
  ushort_t* sQ = sm;                   // [64][64]  xor8
  ushort_t* sK = sm + 4096;            // [128][64] xor8
  ushort_t* sV0 = sm + 12288;          // [64][128] xor16
  ushort_t* sV1 = sm + 20480;
  ushort_t* sP = sm + 28672;           // [64][136] P bf16 / O bounce
  const int tid = threadIdx.x;
  const int lane = tid & 63, wave = tid >> 6;
  const int quad = lane >> 4, l16 = lane & 15;
  const int NQT = QW / 64;
  const int NT = SW / 128;
  const int bx = blockIdx.x;
  const int qt = bx % NQT;
  const int win = (bx / NQT) & 3;
  const int h = (bx / (NQT * 4)) % 12;
  const int b = bx / (NQT * 48);
  const int hc = h * 64;
  const int nq0 = b * TQb + win * QW + qt * 64;
  const int ns_base = b * TSb + win * SW;

  const int r8 = lane >> 3, c8 = lane & 7;
  const int s8 = (c8 ^ r8) * 8;
  const int r16 = lane >> 4, c16 = lane & 15;

  auto stage_k = [&](int ns0) {
#pragma unroll
    for (int i = 0; i < 4; ++i) {
      int row = wave * 32 + i * 8 + r8;
      gl_lds16(Kt + (size_t)(ns0 + row) * 768 + hc + s8, sK + (wave * 32 + i * 8) * 64);
    }
  };
  auto stage_v = [&](int ns0, ushort_t* sV) {
#pragma unroll
    for (int i = 0; i < 4; ++i) {
      int ch = wave * 16 + i * 4 + r16;
      int slot = c16 ^ (i * 4 + r16);
      gl_lds16(Vc + (size_t)(hc + ch) * Ms + ns0 + slot * 8, sV + (wave * 16 + i * 4) * 128);
    }
  };

#pragma unroll
  for (int i = 0; i < 2; ++i) {
    int row = wave * 16 + i * 8 + r8;
    gl_lds16(Qt + (size_t)(nq0 + row) * 768 + hc + s8, sQ + (wave * 16 + i * 8) * 64);
  }
  stage_k(ns_base);
  stage_v(ns_base, sV0);
  __syncthreads();

  short8 qf[2];
#pragma unroll
  for (int ks = 0; ks < 2; ++ks)
    qf[ks] = *reinterpret_cast<const short8*>(
        sQ + (wave * 16 + l16) * 64 + (((ks * 4 + quad) ^ (l16 & 7)) * 8));

  float mr[4], lr[4];
  f32x4 on[4];
#pragma unroll
  for (int r = 0; r < 4; ++r) { mr[r] = -1e30f; lr[r] = 0.f; }
#pragma unroll
  for (int nc = 0; nc < 4; ++nc) on[nc] = (f32x4){0.f, 0.f, 0.f, 0.f};

  for (int t = 0; t < NT; ++t) {
    if (t + 1 < NT) stage_v(ns_base + (t + 1) * 128, (t & 1) ? sV0 : sV1);
    f32x4 sf[8];
#pragma unroll
    for (int nt = 0; nt < 8; ++nt) sf[nt] = (f32x4){0.f, 0.f, 0.f, 0.f};
#pragma unroll
    for (int ks = 0; ks < 2; ++ks) {
#pragma unroll
      for (int nt = 0; nt < 8; ++nt) {
        short8 kf = *reinterpret_cast<const short8*>(
            sK + (nt * 16 + l16) * 64 + (((ks * 4 + quad) ^ (l16 & 7)) * 8));
        sf[nt] = __builtin_amdgcn_mfma_f32_16x16x32_bf16(qf[ks], kf, sf[nt], 0, 0, 0);
      }
    }
    __syncthreads();
    if (t + 1 < NT) stage_k(ns_base + (t + 1) * 128);
#pragma unroll
    for (int r = 0; r < 4; ++r) {
      float m_ = sf[0][r];
#pragma unroll
      for (int nt = 1; nt < 8; ++nt) m_ = fmaxf(m_, sf[nt][r]);
#pragma unroll
      for (int off = 1; off < 16; off <<= 1) m_ = fmaxf(m_, __shfl_xor(m_, off));
      float mnew = fmaxf(mr[r], m_);
      float al = __expf(mr[r] - mnew);
      float ls = 0.f;
      int prow = (wave * 16 + quad * 4 + r) * 136;
#pragma unroll
      for (int nt = 0; nt < 8; ++nt) {
        float p = __expf(sf[nt][r] - mnew);
        ls += p;
        sP[prow + nt * 16 + l16] = f2b(p);
      }
#pragma unroll
      for (int off = 1; off < 16; off <<= 1) ls += __shfl_xor(ls, off);
      lr[r] = lr[r] * al + ls;
      mr[r] = mnew;
#pragma unroll
      for (int nc = 0; nc < 4; ++nc) on[nc][r] *= al;
    }
    const ushort_t* sV = (t & 1) ? sV1 : sV0;
#pragma unroll
    for (int ks = 0; ks < 4; ++ks) {
      short8 pf = *reinterpret_cast<const short8*>(sP + (wave * 16 + l16) * 136 + ks * 32 + quad * 8);
#pragma unroll
      for (int nc = 0; nc < 4; ++nc) {
        short8 vf = *reinterpret_cast<const short8*>(
            sV + (nc * 16 + l16) * 128 + (((ks * 4 + quad) ^ l16) * 8));
        on[nc] = __builtin_amdgcn_mfma_f32_16x16x32_bf16(pf, vf, on[nc], 0, 0, 0);
      }
    }
    if (t + 1 < NT) __syncthreads();
  }
#pragma unroll
  for (int r = 0; r < 4; ++r) {
    float inv = 1.f / lr[r];
    int prow = (wave * 16 + quad * 4 + r) * 136;
#pragma unroll
    for (int nc = 0; nc < 4; ++nc)
      sP[prow + nc * 16 + l16] = f2b(on[nc][r] * inv);
  }
  __syncthreads();
#pragma unroll
  for (int i = 0; i < 2; ++i) {
    int c = i * 256 + tid;
    int row = c >> 3, cc = c & 7;
    *reinterpret_cast<uint4*>(Ot + (size_t)(nq0 + row) * 768 + hc + cc * 8) =
        *reinterpret_cast<const uint4*>(sP + row * 136 + cc * 8);
  }
}

// ---------------------------------------------------------------------------
extern "C" void kernel_launch(void* const* d_in, const int* in_sizes, int n_in,
                              void* d_out, int out_size, void* d_ws, size_t ws_size,
                              hipStream_t stream) {
  (void)in_sizes; (void)n_in; (void)out_size; (void)ws_size;
  const float* video = (const float*)d_in[0];
  const float* audio = (const float*)d_in[1];
  const float* vn_s = (const float*)d_in[2];
  const float* vn_b = (const float*)d_in[3];
  const float* an_s = (const float*)d_in[4];
  const float* an_b = (const float*)d_in[5];
  const float* vqkv_w = (const float*)d_in[6];
  const float* vqkv_b = (const float*)d_in[7];
  const float* aqkv_w = (const float*)d_in[8];
  const float* aqkv_b = (const float*)d_in[9];
  const float* vproj_w = (const float*)d_in[10];
  const float* vproj_b = (const float*)d_in[11];
  const float* aproj_w = (const float*)d_in[12];
  const float* aproj_b = (const float*)d_in[13];

  float* out_v = (float*)d_out;
  float* out_a = out_v + (size_t)4 * 16 * 768 * 16 * 16;

  char* ws = (char*)d_ws;
  size_t off = 0;
  auto carve = [&](size_t bytes) {
    char* p = ws + off;
    off += (bytes + 255) & ~(size_t)255;
    return p;
  };
  float* mu = (float*)carve(256 * 4);
  float* rs = (float*)carve(256 * 4);
  float* part = (float*)carve(2560 * 2 * 4);
  ushort_t* Xv = (ushort_t*)carve((size_t)16384 * 768 * 2);
  ushort_t* Xa = (ushort_t*)carve((size_t)4096 * 768 * 2);
  ushort_t* Wqv = (ushort_t*)carve((size_t)2304 * 768 * 2);
  ushort_t* Wqa = (ushort_t*)carve((size_t)2304 * 768 * 2);
  ushort_t* Wpv = (ushort_t*)carve((size_t)768 * 768 * 2);
  ushort_t* Wpa = (ushort_t*)carve((size_t)768 * 768 * 2);
  ushort_t* Qv = (ushort_t*)carve((size_t)16384 * 768 * 2);
  ushort_t* Kv = (ushort_t*)carve((size_t)16384 * 768 * 2);
  ushort_t* Vv = (ushort_t*)carve((size_t)16384 * 768 * 2);
  ushort_t* Qa = (ushort_t*)carve((size_t)4096 * 768 * 2);
  ushort_t* Ka = (ushort_t*)carve((size_t)4096 * 768 * 2);
  ushort_t* Va = (ushort_t*)carve((size_t)4096 * 768 * 2);
  ushort_t* Ov = Xv;  // alias: X no longer needed after QKV GEMM
  ushort_t* Oa = Xa;

  wcvt_kernel<<<1024, 256, 0, stream>>>(vqkv_w, aqkv_w, vproj_w, aproj_w, Wqv, Wqa, Wpv, Wpa);
  gn_partial_kernel<<<2560, 256, 0, stream>>>(video, audio, part);
  gn_final_kernel<<<1, 256, 0, stream>>>(part, mu, rs);
  norm_video_kernel<<<1536, 256, 0, stream>>>(video, mu, rs, vn_s, vn_b, Xv);
  norm_audio_kernel<<<384, 256, 0, stream>>>(audio, mu, rs, an_s, an_b, Xa);
  gemm256_kernel<0><<<dim3(9, 64), 512, 0, stream>>>(Xv, Wqv, vqkv_b, Qv, Kv, Vv, 16384);
  gemm256_kernel<0><<<dim3(9, 16), 512, 0, stream>>>(Xa, Wqa, aqkv_b, Qa, Ka, Va, 4096);
  // video queries attend audio windows: QW=1024, SW=256
  attn_mfma_kernel<1024, 256><<<3072, 256, 0, stream>>>(Qv, Ka, Va, Ov, 4096, 1024, 4096);
  // audio queries attend video windows: QW=256, SW=1024
  attn_mfma_kernel<256, 1024><<<768, 256, 0, stream>>>(Qa, Kv, Vv, Oa, 1024, 4096, 16384);
  gemm256_kernel<1><<<dim3(3, 64), 512, 0, stream>>>(Ov, Wpv, vproj_b, (void*)out_v, (void*)video, nullptr, 16384);
  gemm_kernel<2><<<dim3(6, 32), 256, 0, stream>>>(Oa, Wpa, aproj_b, (void*)out_a, (void*)audio, nullptr, 4096);
}

// Round 5
// 379.736 us; speedup vs baseline: 1.1489x; 1.1489x over previous
//
#include <hip/hip_runtime.h>
#include <hip/hip_bf16.h>

typedef unsigned short ushort_t;
typedef __attribute__((ext_vector_type(8))) short short8;
typedef __attribute__((ext_vector_type(4))) float f32x4;

#define DI __device__ __forceinline__

DI float b2f(unsigned int u16) {
  union { unsigned int i; float f; } v;
  v.i = u16 << 16;
  return v.f;
}
DI ushort_t f2b(float f) {
  union { float f; unsigned int u; } v; v.f = f;
  unsigned int r = v.u + 0x7FFFu + ((v.u >> 16) & 1u);
  return (ushort_t)(r >> 16);
}

// async global->LDS 16B copy: LDS dest is wave-uniform base + lane*16
DI void gl_lds16(const ushort_t* g, ushort_t* l) {
  __builtin_amdgcn_global_load_lds(
      (const __attribute__((address_space(1))) unsigned int*)g,
      (__attribute__((address_space(3))) unsigned int*)l, 16, 0, 0);
}

// ---------------------------------------------------------------------------
// Fused: GroupNorm partial stats (blocks 0..2559) + weight bf16 cvt (2560..3583)
// ---------------------------------------------------------------------------
__global__ __launch_bounds__(256) void fused_pre_kernel(
    const float* __restrict__ video, const float* __restrict__ audio,
    float* __restrict__ part,
    const float* __restrict__ w0, const float* __restrict__ w1,
    const float* __restrict__ w2, const float* __restrict__ w3,
    ushort_t* __restrict__ o0, ushort_t* __restrict__ o1,
    ushort_t* __restrict__ o2, ushort_t* __restrict__ o3) {
  const int bid = blockIdx.x;
  const int tid = threadIdx.x;
  __shared__ float red[8];
  if (bid < 2560) {
    float s = 0.f, ss = 0.f;
    if (bid < 2048) {
      int bg = bid >> 4, f = bid & 15;
      int b = bg >> 5, g = bg & 31;
      const float* base = video + ((size_t)((b * 16 + f) * 768 + g * 24)) * 256 + tid;
#pragma unroll
      for (int cl = 0; cl < 24; ++cl) {
        float v = base[cl * 256];
        s += v; ss += v * v;
      }
    } else {
      int a = bid - 2048;
      int bg = a >> 2, p = a & 3;
      int b = bg >> 5, g = bg & 31;
      const float* base = audio + ((size_t)(b * 768 + g * 24)) * 1024 + p * 256 + tid;
#pragma unroll
      for (int cl = 0; cl < 24; ++cl) {
        float v = base[cl * 1024];
        s += v; ss += v * v;
      }
    }
    for (int off = 32; off > 0; off >>= 1) { s += __shfl_down(s, off, 64); ss += __shfl_down(ss, off, 64); }
    int wv = tid >> 6, ln = tid & 63;
    if (ln == 0) { red[wv * 2] = s; red[wv * 2 + 1] = ss; }
    __syncthreads();
    if (tid == 0) {
      part[bid * 2] = red[0] + red[2] + red[4] + red[6];
      part[bid * 2 + 1] = red[1] + red[3] + red[5] + red[7];
    }
  } else {
    const int n1 = 2304 * 768, n3 = 768 * 768;
    const int total = 2 * n1 + 2 * n3;
    int wb = bid - 2560;
    for (int i = wb * 256 + tid; i < total; i += 1024 * 256) {
      if (i < n1) o0[i] = f2b(w0[i]);
      else if (i < 2 * n1) o1[i - n1] = f2b(w1[i - n1]);
      else if (i < 2 * n1 + n3) o2[i - 2 * n1] = f2b(w2[i - 2 * n1]);
      else o3[i - 2 * n1 - n3] = f2b(w3[i - 2 * n1 - n3]);
    }
  }
}

// ---------------------------------------------------------------------------
// Fused normalize (gn_final folded in: per-block channel stats from `part`).
// Blocks 0..1535: video -> Xv[n][c]; 1536..1919: audio -> Xa[n][c].
// ---------------------------------------------------------------------------
__global__ __launch_bounds__(256) void norm_fused_kernel(
    const float* __restrict__ video, const float* __restrict__ audio,
    const float* __restrict__ part,
    const float* __restrict__ vsc, const float* __restrict__ vbi,
    const float* __restrict__ asc, const float* __restrict__ abi,
    ushort_t* __restrict__ Xv, ushort_t* __restrict__ Xa) {
  __shared__ float T[32][257];
  __shared__ float shm[32], shr[32];
  const int bx = blockIdx.x;
  const int tid = threadIdx.x;
  if (bx < 1536) {
    const int bf = bx / 24, ct = bx % 24;
    const int b = bf >> 4, f = bf & 15;
    const int c0 = ct * 32;
    if (tid < 32) {
      int c = c0 + tid, g = c / 24;
      float s = 0.f, ss = 0.f;
#pragma unroll
      for (int i = 0; i < 16; ++i) {
        s += part[((b * 32 + g) * 16 + i) * 2];
        ss += part[((b * 32 + g) * 16 + i) * 2 + 1];
      }
      const float N = 24.f * 4096.f;
      float m = s / N;
      shm[tid] = m;
      shr[tid] = rsqrtf(ss / N - m * m + 1e-5f);
    }
    __syncthreads();
    for (int i = 0; i < 32; ++i) {
      int c = c0 + i;
      float v = video[((size_t)((b * 16 + f) * 768 + c)) * 256 + tid];
      T[i][tid] = (v - shm[i]) * shr[i] * vsc[c] + vbi[c];
    }
    __syncthreads();
    for (int i = 0; i < 32; ++i) {
      int id = i * 256 + tid;
      int c = id & 31, hw = id >> 5;
      Xv[((size_t)(b * 4096 + f * 256 + hw)) * 768 + c0 + c] = f2b(T[c][hw]);
    }
  } else {
    const int ax = bx - 1536;
    const int bt = ax / 24, ct = ax % 24;
    const int b = bt >> 2, t0 = (bt & 3) * 256;
    const int c0 = ct * 32;
    if (tid < 32) {
      int c = c0 + tid, g = c / 24;
      float s = 0.f, ss = 0.f;
#pragma unroll
      for (int i = 0; i < 4; ++i) {
        s += part[(2048 + (b * 32 + g) * 4 + i) * 2];
        ss += part[(2048 + (b * 32 + g) * 4 + i) * 2 + 1];
      }
      const float N = 24.f * 1024.f;
      float m = s / N;
      shm[tid] = m;
      shr[tid] = rsqrtf(ss / N - m * m + 1e-5f);
    }
    __syncthreads();
    for (int i = 0; i < 32; ++i) {
      int c = c0 + i;
      float v = audio[((size_t)(b * 768 + c)) * 1024 + t0 + tid];
      T[i][tid] = (v - shm[i]) * shr[i] * asc[c] + abi[c];
    }
    __syncthreads();
    for (int i = 0; i < 32; ++i) {
      int id = i * 256 + tid;
      int c = id & 31, tt = id >> 5;
      Xa[((size_t)(b * 1024 + t0 + tt)) * 768 + c0 + c] = f2b(T[c][tt]);
    }
  }
}

// ---------------------------------------------------------------------------
// Fused QKV GEMM (video blocks 0..2303, audio 2304..2879).
// 128x128 tile, 2-phase dbuf gl_lds16 staging, XOR chunk swizzle both sides,
// segment-local XCD bijective block swizzle. Q section pre-scaled by 0.125.
// ---------------------------------------------------------------------------
__global__ __launch_bounds__(256) void qkv_fused_kernel(
    const ushort_t* __restrict__ Xv, const ushort_t* __restrict__ Xa,
    const ushort_t* __restrict__ Wqv, const ushort_t* __restrict__ Wqa,
    const float* __restrict__ vqkv_b, const float* __restrict__ aqkv_b,
    ushort_t* __restrict__ Qv, ushort_t* __restrict__ Kv, ushort_t* __restrict__ Vv,
    ushort_t* __restrict__ Qa, ushort_t* __restrict__ Ka, ushort_t* __restrict__ Va) {
  __shared__ ushort_t sm[32768];  // 64 KiB dbuf
  const int bid = blockIdx.x;
  const int tid = threadIdx.x;
  const int lane = tid & 63, wave = tid >> 6;
  const int quad = lane >> 4, l16 = lane & 15;

  const bool isv = bid < 2304;
  const int lb = isv ? bid : bid - 2304;
  const int nwg = isv ? 2304 : 576;
  const ushort_t* A = isv ? Xv : Xa;
  const ushort_t* W = isv ? Wqv : Wqa;
  const float* bias = isv ? vqkv_b : aqkv_b;
  ushort_t* pQ = isv ? Qv : Qa;
  ushort_t* pK = isv ? Kv : Ka;
  ushort_t* pV = isv ? Vv : Va;
  const int M = isv ? 16384 : 4096;

  const int lid = (lb & 7) * (nwg >> 3) + (lb >> 3);
  const int n0 = (lid % 18) * 128, m0 = (lid / 18) * 128;
  const int wm = (wave & 1) * 64, wn = (wave >> 1) * 64;

  const int srow = wave * 32 + (lane >> 3);
  const int sq = ((lane & 7) ^ (lane >> 3)) * 8;
  const ushort_t* gA = A + (size_t)(m0 + srow) * 768 + sq;
  const ushort_t* gB = W + (size_t)(n0 + srow) * 768 + sq;

  f32x4 acc[4][4];
#pragma unroll
  for (int i = 0; i < 4; ++i)
#pragma unroll
    for (int j = 0; j < 4; ++j) acc[i][j] = (f32x4){0.f, 0.f, 0.f, 0.f};

  auto stage = [&](int kc, int cur) {
    ushort_t* lA = sm + cur * 8192 + wave * 2048;
    ushort_t* lB = sm + 16384 + cur * 8192 + wave * 2048;
#pragma unroll
    for (int i = 0; i < 4; ++i) {
      gl_lds16(gA + (size_t)i * 8 * 768 + kc, lA + i * 512);
      gl_lds16(gB + (size_t)i * 8 * 768 + kc, lB + i * 512);
    }
  };

  stage(0, 0);
  __syncthreads();
  int cur = 0;
  for (int t = 0; t < 12; ++t) {
    if (t < 11) stage((t + 1) * 64, cur ^ 1);
    const ushort_t* cA = sm + cur * 8192;
    const ushort_t* cB = sm + 16384 + cur * 8192;
#pragma unroll
    for (int ks = 0; ks < 2; ++ks) {
      short8 av[4], bv[4];
#pragma unroll
      for (int im = 0; im < 4; ++im) {
        int rr = wm + im * 16 + l16;
        av[im] = *reinterpret_cast<const short8*>(
            cA + rr * 64 + (((ks * 4 + quad) ^ (rr & 7)) * 8));
      }
#pragma unroll
      for (int in = 0; in < 4; ++in) {
        int rr = wn + in * 16 + l16;
        bv[in] = *reinterpret_cast<const short8*>(
            cB + rr * 64 + (((ks * 4 + quad) ^ (rr & 7)) * 8));
      }
#pragma unroll
      for (int im = 0; im < 4; ++im)
#pragma unroll
        for (int in = 0; in < 4; ++in)
          acc[im][in] = __builtin_amdgcn_mfma_f32_16x16x32_bf16(av[im], bv[in], acc[im][in], 0, 0, 0);
    }
    __syncthreads();
    cur ^= 1;
  }

  ushort_t* sC = sm;  // epilogue scratch [128][136] bf16
  const int section = n0 / 768;  // 0=Q 1=K 2=V
  const int obase = n0 - section * 768;
  if (section < 2) {
    const float qs = (section == 0) ? 0.125f : 1.0f;  // fold qk scale into Q
#pragma unroll
    for (int in = 0; in < 4; ++in) {
      int ol = wn + in * 16 + l16;
      float bv_ = bias[n0 + ol];
#pragma unroll
      for (int im = 0; im < 4; ++im)
#pragma unroll
        for (int r = 0; r < 4; ++r) {
          int row = wm + im * 16 + quad * 4 + r;
          sC[row * 136 + ol] = f2b((acc[im][in][r] + bv_) * qs);
        }
    }
    __syncthreads();
    ushort_t* dst = (section == 0) ? pQ : pK;
#pragma unroll
    for (int i = 0; i < 8; ++i) {
      int cid = i * 256 + tid;
      int row = cid >> 4, ch = cid & 15;
      *reinterpret_cast<uint4*>(dst + (size_t)(m0 + row) * 768 + obase + ch * 8) =
          *reinterpret_cast<const uint4*>(sC + row * 136 + ch * 8);
    }
  } else {
#pragma unroll
    for (int in = 0; in < 4; ++in) {
      int ol = wn + in * 16 + l16;
      float bv_ = bias[n0 + ol];
#pragma unroll
      for (int im = 0; im < 4; ++im)
#pragma unroll
        for (int r = 0; r < 4; ++r) {
          int mr = wm + im * 16 + quad * 4 + r;
          sC[ol * 136 + mr] = f2b(acc[im][in][r] + bv_);
        }
    }
    __syncthreads();
#pragma unroll
    for (int i = 0; i < 8; ++i) {
      int cid = i * 256 + tid;
      int o = cid >> 4, ch = cid & 15;
      *reinterpret_cast<uint4*>(pV + (size_t)(obase + o) * M + m0 + ch * 8) =
          *reinterpret_cast<const uint4*>(sC + o * 136 + ch * 8);
    }
  }
}

// ---------------------------------------------------------------------------
// Fused proj GEMM + residual (video blocks 0..767 MODE1, audio 768..959 MODE2)
// ---------------------------------------------------------------------------
__global__ __launch_bounds__(256) void proj_fused_kernel(
    const ushort_t* __restrict__ Ov, const ushort_t* __restrict__ Oa,
    const ushort_t* __restrict__ Wpv, const ushort_t* __restrict__ Wpa,
    const float* __restrict__ vproj_b, const float* __restrict__ aproj_b,
    float* __restrict__ out_v, const float* __restrict__ video,
    float* __restrict__ out_a, const float* __restrict__ audio) {
  __shared__ ushort_t sm[32768];
  const int bid = blockIdx.x;
  const int tid = threadIdx.x;
  const int lane = tid & 63, wave = tid >> 6;
  const int quad = lane >> 4, l16 = lane & 15;

  const bool isv = bid < 768;
  const int lb = isv ? bid : bid - 768;
  const int nwg = isv ? 768 : 192;
  const ushort_t* A = isv ? Ov : Oa;
  const ushort_t* W = isv ? Wpv : Wpa;
  const float* bias = isv ? vproj_b : aproj_b;
  float* outp = isv ? out_v : out_a;
  const float* resp = isv ? video : audio;

  const int lid = (lb & 7) * (nwg >> 3) + (lb >> 3);
  const int n0 = (lid % 6) * 128, m0 = (lid / 6) * 128;
  const int wm = (wave & 1) * 64, wn = (wave >> 1) * 64;

  const int srow = wave * 32 + (lane >> 3);
  const int sq = ((lane & 7) ^ (lane >> 3)) * 8;
  const ushort_t* gA = A + (size_t)(m0 + srow) * 768 + sq;
  const ushort_t* gB = W + (size_t)(n0 + srow) * 768 + sq;

  f32x4 acc[4][4];
#pragma unroll
  for (int i = 0; i < 4; ++i)
#pragma unroll
    for (int j = 0; j < 4; ++j) acc[i][j] = (f32x4){0.f, 0.f, 0.f, 0.f};

  auto stage = [&](int kc, int cur) {
    ushort_t* lA = sm + cur * 8192 + wave * 2048;
    ushort_t* lB = sm + 16384 + cur * 8192 + wave * 2048;
#pragma unroll
    for (int i = 0; i < 4; ++i) {
      gl_lds16(gA + (size_t)i * 8 * 768 + kc, lA + i * 512);
      gl_lds16(gB + (size_t)i * 8 * 768 + kc, lB + i * 512);
    }
  };

  stage(0, 0);
  __syncthreads();
  int cur = 0;
  for (int t = 0; t < 12; ++t) {
    if (t < 11) stage((t + 1) * 64, cur ^ 1);
    const ushort_t* cA = sm + cur * 8192;
    const ushort_t* cB = sm + 16384 + cur * 8192;
#pragma unroll
    for (int ks = 0; ks < 2; ++ks) {
      short8 av[4], bv[4];
#pragma unroll
      for (int im = 0; im < 4; ++im) {
        int rr = wm + im * 16 + l16;
        av[im] = *reinterpret_cast<const short8*>(
            cA + rr * 64 + (((ks * 4 + quad) ^ (rr & 7)) * 8));
      }
#pragma unroll
      for (int in = 0; in < 4; ++in) {
        int rr = wn + in * 16 + l16;
        bv[in] = *reinterpret_cast<const short8*>(
            cB + rr * 64 + (((ks * 4 + quad) ^ (rr & 7)) * 8));
      }
#pragma unroll
      for (int im = 0; im < 4; ++im)
#pragma unroll
        for (int in = 0; in < 4; ++in)
          acc[im][in] = __builtin_amdgcn_mfma_f32_16x16x32_bf16(av[im], bv[in], acc[im][in], 0, 0, 0);
    }
    __syncthreads();
    cur ^= 1;
  }

  ushort_t* sC = sm;  // [128 o][136] bf16, transposed store
#pragma unroll
  for (int in = 0; in < 4; ++in) {
    int ol = wn + in * 16 + l16;
    float bv_ = bias[n0 + ol];
#pragma unroll
    for (int im = 0; im < 4; ++im)
#pragma unroll
      for (int r = 0; r < 4; ++r) {
        int mr = wm + im * 16 + quad * 4 + r;
        sC[ol * 136 + mr] = f2b(acc[im][in][r] + bv_);
      }
  }
  __syncthreads();
#pragma unroll
  for (int i = 0; i < 16; ++i) {
    int cid = i * 256 + tid;
    int o = cid >> 5, ch = cid & 31;
    uint2 pk = *reinterpret_cast<const uint2*>(sC + o * 136 + ch * 4);
    size_t gidx;
    if (isv) {
      int b = m0 >> 12, f = (m0 >> 8) & 15, hw0 = m0 & 255;
      gidx = ((size_t)((b * 16 + f) * 768 + n0 + o)) * 256 + hw0 + ch * 4;
    } else {
      int b = m0 >> 10, t0 = m0 & 1023;
      gidx = ((size_t)(b * 768 + n0 + o)) * 1024 + t0 + ch * 4;
    }
    float4 rv = *reinterpret_cast<const float4*>(resp + gidx);
    float4 ov;
    ov.x = rv.x + b2f(pk.x & 0xffff);
    ov.y = rv.y + b2f(pk.x >> 16);
    ov.z = rv.z + b2f(pk.y & 0xffff);
    ov.w = rv.w + b2f(pk.y >> 16);
    *reinterpret_cast<float4*>(outp + gidx) = ov;
  }
}

// ---------------------------------------------------------------------------
// Fused MFMA flash attention: blocks 0..3071 video-q/audio-kv (QW=1024,SW=256),
// blocks 3072..3839 audio-q/video-kv (QW=256,SW=1024). Runtime shape params.
// Async gl_lds16 staging (XOR-swizzled both sides), V double-buffered;
// V(t+1) before QK(t), K(t+1) after mid barrier. Q pre-scaled in QKV GEMM.
// ---------------------------------------------------------------------------
__global__ __launch_bounds__(256) void attn_fused_kernel(
    const ushort_t* __restrict__ Qv, const ushort_t* __restrict__ Ka,
    const ushort_t* __restrict__ Va, ushort_t* __restrict__ Ov,
    const ushort_t* __restrict__ Qa, const ushort_t* __restrict__ Kv,
    const ushort_t* __restrict__ Vv, ushort_t* __restrict__ Oa) {
  __shared__ ushort_t sm[37376];       // 74752 B
  ushort_t* sQ = sm;                   // [64][64]  xor8
  ushort_t* sK = sm + 4096;            // [128][64] xor8
  ushort_t* sV0 = sm + 12288;          // [64][128] xor16
  ushort_t* sV1 = sm + 20480;
  ushort_t* sP = sm + 28672;           // [64][136] P bf16 / O bounce
  const int tid = threadIdx.x;
  const int lane = tid & 63, wave = tid >> 6;
  const int quad = lane >> 4, l16 = lane & 15;
  const int bx = blockIdx.x;

  const bool isv = bx < 3072;
  const ushort_t* Qt = isv ? Qv : Qa;
  const ushort_t* Kt = isv ? Ka : Kv;
  const ushort_t* Vc = isv ? Va : Vv;
  ushort_t* Ot = isv ? Ov : Oa;
  const int lb = isv ? bx : bx - 3072;
  const int qlog = isv ? 4 : 2;        // NQT = 16 / 4
  const int NT = isv ? 2 : 8;          // SW/128
  const int QW = isv ? 1024 : 256;
  const int SW = isv ? 256 : 1024;
  const int TQb = isv ? 4096 : 1024;
  const int TSb = isv ? 1024 : 4096;
  const int Ms = isv ? 4096 : 16384;

  const int qt = lb & ((1 << qlog) - 1);
  const int win = (lb >> qlog) & 3;
  const int whb = lb >> (qlog + 2);
  const int h = whb % 12;
  const int batch = whb / 12;
  const int hc = h * 64;
  const int nq0 = batch * TQb + win * QW + qt * 64;
  const int ns_base = batch * TSb + win * SW;

  const int r8 = lane >> 3, c8 = lane & 7;
  const int s8 = (c8 ^ r8) * 8;
  const int r16 = lane >> 4, c16 = lane & 15;

  auto stage_k = [&](int ns0) {
#pragma unroll
    for (int i = 0; i < 4; ++i) {
      int row = wave * 32 + i * 8 + r8;
      gl_lds16(Kt + (size_t)(ns0 + row) * 768 + hc + s8, sK + (wave * 32 + i * 8) * 64);
    }
  };
  auto stage_v = [&](int ns0, ushort_t* sV) {
#pragma unroll
    for (int i = 0; i < 4; ++i) {
      int ch = wave * 16 + i * 4 + r16;
      int slot = c16 ^ (i * 4 + r16);
      gl_lds16(Vc + (size_t)(hc + ch) * Ms + ns0 + slot * 8, sV + (wave * 16 + i * 4) * 128);
    }
  };

#pragma unroll
  for (int i = 0; i < 2; ++i) {
    int row = wave * 16 + i * 8 + r8;
    gl_lds16(Qt + (size_t)(nq0 + row) * 768 + hc + s8, sQ + (wave * 16 + i * 8) * 64);
  }
  stage_k(ns_base);
  stage_v(ns_base, sV0);
  __syncthreads();

  short8 qf[2];
#pragma unroll
  for (int ks = 0; ks < 2; ++ks)
    qf[ks] = *reinterpret_cast<const short8*>(
        sQ + (wave * 16 + l16) * 64 + (((ks * 4 + quad) ^ (l16 & 7)) * 8));

  float mr[4], lr[4];
  f32x4 on[4];
#pragma unroll
  for (int r = 0; r < 4; ++r) { mr[r] = -1e30f; lr[r] = 0.f; }
#pragma unroll
  for (int nc = 0; nc < 4; ++nc) on[nc] = (f32x4){0.f, 0.f, 0.f, 0.f};

  for (int t = 0; t < NT; ++t) {
    if (t + 1 < NT) stage_v(ns_base + (t + 1) * 128, (t & 1) ? sV0 : sV1);
    f32x4 sf[8];
#pragma unroll
    for (int nt = 0; nt < 8; ++nt) sf[nt] = (f32x4){0.f, 0.f, 0.f, 0.f};
#pragma unroll
    for (int ks = 0; ks < 2; ++ks) {
#pragma unroll
      for (int nt = 0; nt < 8; ++nt) {
        short8 kf = *reinterpret_cast<const short8*>(
            sK + (nt * 16 + l16) * 64 + (((ks * 4 + quad) ^ (l16 & 7)) * 8));
        sf[nt] = __builtin_amdgcn_mfma_f32_16x16x32_bf16(qf[ks], kf, sf[nt], 0, 0, 0);
      }
    }
    __syncthreads();
    if (t + 1 < NT) stage_k(ns_base + (t + 1) * 128);
#pragma unroll
    for (int r = 0; r < 4; ++r) {
      float m_ = sf[0][r];
#pragma unroll
      for (int nt = 1; nt < 8; ++nt) m_ = fmaxf(m_, sf[nt][r]);
#pragma unroll
      for (int off = 1; off < 16; off <<= 1) m_ = fmaxf(m_, __shfl_xor(m_, off));
      float mnew = fmaxf(mr[r], m_);
      float al = __expf(mr[r] - mnew);
      float ls = 0.f;
      int prow = (wave * 16 + quad * 4 + r) * 136;
#pragma unroll
      for (int nt = 0; nt < 8; ++nt) {
        float p = __expf(sf[nt][r] - mnew);
        ls += p;
        sP[prow + nt * 16 + l16] = f2b(p);
      }
#pragma unroll
      for (int off = 1; off < 16; off <<= 1) ls += __shfl_xor(ls, off);
      lr[r] = lr[r] * al + ls;
      mr[r] = mnew;
#pragma unroll
      for (int nc = 0; nc < 4; ++nc) on[nc][r] *= al;
    }
    const ushort_t* sV = (t & 1) ? sV1 : sV0;
#pragma unroll
    for (int ks = 0; ks < 4; ++ks) {
      short8 pf = *reinterpret_cast<const short8*>(sP + (wave * 16 + l16) * 136 + ks * 32 + quad * 8);
#pragma unroll
      for (int nc = 0; nc < 4; ++nc) {
        short8 vf = *reinterpret_cast<const short8*>(
            sV + (nc * 16 + l16) * 128 + (((ks * 4 + quad) ^ l16) * 8));
        on[nc] = __builtin_amdgcn_mfma_f32_16x16x32_bf16(pf, vf, on[nc], 0, 0, 0);
      }
    }
    if (t + 1 < NT) __syncthreads();
  }
#pragma unroll
  for (int r = 0; r < 4; ++r) {
    float inv = 1.f / lr[r];
    int prow = (wave * 16 + quad * 4 + r) * 136;
#pragma unroll
    for (int nc = 0; nc < 4; ++nc)
      sP[prow + nc * 16 + l16] = f2b(on[nc][r] * inv);
  }
  __syncthreads();
#pragma unroll
  for (int i = 0; i < 2; ++i) {
    int c = i * 256 + tid;
    int row = c >> 3, cc = c & 7;
    *reinterpret_cast<uint4*>(Ot + (size_t)(nq0 + row) * 768 + hc + cc * 8) =
        *reinterpret_cast<const uint4*>(sP + row * 136 + cc * 8);
  }
}

// ---------------------------------------------------------------------------
extern "C" void kernel_launch(void* const* d_in, const int* in_sizes, int n_in,
                              void* d_out, int out_size, void* d_ws, size_t ws_size,
                              hipStream_t stream) {
  (void)in_sizes; (void)n_in; (void)out_size; (void)ws_size;
  const float* video = (const float*)d_in[0];
  const float* audio = (const float*)d_in[1];
  const float* vn_s = (const float*)d_in[2];
  const float* vn_b = (const float*)d_in[3];
  const float* an_s = (const float*)d_in[4];
  const float* an_b = (const float*)d_in[5];
  const float* vqkv_w = (const float*)d_in[6];
  const float* vqkv_b = (const float*)d_in[7];
  const float* aqkv_w = (const float*)d_in[8];
  const float* aqkv_b = (const float*)d_in[9];
  const float* vproj_w = (const float*)d_in[10];
  const float* vproj_b = (const float*)d_in[11];
  const float* aproj_w = (const float*)d_in[12];
  const float* aproj_b = (const float*)d_in[13];

  float* out_v = (float*)d_out;
  float* out_a = out_v + (size_t)4 * 16 * 768 * 16 * 16;

  char* ws = (char*)d_ws;
  size_t off = 0;
  auto carve = [&](size_t bytes) {
    char* p = ws + off;
    off += (bytes + 255) & ~(size_t)255;
    return p;
  };
  float* part = (float*)carve(2560 * 2 * 4);
  ushort_t* Xv = (ushort_t*)carve((size_t)16384 * 768 * 2);
  ushort_t* Xa = (ushort_t*)carve((size_t)4096 * 768 * 2);
  ushort_t* Wqv = (ushort_t*)carve((size_t)2304 * 768 * 2);
  ushort_t* Wqa = (ushort_t*)carve((size_t)2304 * 768 * 2);
  ushort_t* Wpv = (ushort_t*)carve((size_t)768 * 768 * 2);
  ushort_t* Wpa = (ushort_t*)carve((size_t)768 * 768 * 2);
  ushort_t* Qv = (ushort_t*)carve((size_t)16384 * 768 * 2);
  ushort_t* Kv = (ushort_t*)carve((size_t)16384 * 768 * 2);
  ushort_t* Vv = (ushort_t*)carve((size_t)16384 * 768 * 2);
  ushort_t* Qa = (ushort_t*)carve((size_t)4096 * 768 * 2);
  ushort_t* Ka = (ushort_t*)carve((size_t)4096 * 768 * 2);
  ushort_t* Va = (ushort_t*)carve((size_t)4096 * 768 * 2);
  ushort_t* Ov = Xv;  // alias: X no longer needed after QKV GEMM
  ushort_t* Oa = Xa;

  fused_pre_kernel<<<3584, 256, 0, stream>>>(video, audio, part,
                                             vqkv_w, aqkv_w, vproj_w, aproj_w,
                                             Wqv, Wqa, Wpv, Wpa);
  norm_fused_kernel<<<1920, 256, 0, stream>>>(video, audio, part,
                                              vn_s, vn_b, an_s, an_b, Xv, Xa);
  qkv_fused_kernel<<<2880, 256, 0, stream>>>(Xv, Xa, Wqv, Wqa, vqkv_b, aqkv_b,
                                             Qv, Kv, Vv, Qa, Ka, Va);
  attn_fused_kernel<<<3840, 256, 0, stream>>>(Qv, Ka, Va, Ov, Qa, Kv, Vv, Oa);
  proj_fused_kernel<<<960, 256, 0, stream>>>(Ov, Oa, Wpv, Wpa, vproj_b, aproj_b,
                                             out_v, video, out_a, audio);
}